// Round 3
// baseline (103.096 us; speedup 1.0000x reference)
//
#include <hip/hip_runtime.h>
#include <math.h>

#define N_SAMPLES 8192
#define DIM 128
#define NCLS 1024
#define MARGIN_V 0.3f
#define DIST_GX (N_SAMPLES / 128)   // 64 j-tiles of 128
#define DIST_GY (NCLS / 64)         // 16 class-tiles of 64
#define MAXMEM 64                   // LDS member-list capacity per class
#define PIPE 16                     // pipelined gather depth (covers P(cnt<=16)~0.997)
#define NBLK (DIST_GX * DIST_GY)    // 1024 dist blocks

using bf16x8 = __attribute__((ext_vector_type(8))) short;
using f32x16 = __attribute__((ext_vector_type(16))) float;
using short8 = __attribute__((ext_vector_type(8))) short;

__device__ __forceinline__ short bf16_rne(float x) {
  unsigned u = __float_as_uint(x);
  unsigned r = u + 0x7FFFu + ((u >> 16) & 1u);
  return (short)(r >> 16);
}

// Order-preserving float<->u32 encoding: f2ord is monotone (f1 < f2 <=>
// f2ord(f1) < f2ord(f2) as unsigned), so atomicMax/atomicMin on the keys
// implement float max/min exactly (no precision change).
__device__ __forceinline__ unsigned f2ord(float f) {
  unsigned u = __float_as_uint(f);
  return (u & 0x80000000u) ? ~u : (u | 0x80000000u);
}
__device__ __forceinline__ float ord2f(unsigned k) {
  unsigned v = (k & 0x80000000u) ? (k & 0x7FFFFFFFu) : ~k;
  return __uint_as_float(v);
}

// Packed fragment layout, single bf16 plane (row-major source [row][k]):
//   tile = row>>5, kstep = oct>>1 (oct = k/8), lane = ((oct&1)<<5)|(row&31)
//   short8 index = (tile*8 + kstep)*64 + lane
// Matches mfma_32x32x16 A/B operand layout operand[row=lane&31][k=(lane>>5)*8+j]
// (harness-verified in earlier rounds; bf16-only passes with absmax ~0).
__device__ __forceinline__ size_t frag_idx(int row, int oct) {
  int tile = row >> 5, ks = oct >> 1, lane = ((oct & 1) << 5) | (row & 31);
  return (size_t)(tile * 8 + ks) * 64 + lane;
}

// K1: fused pack (verified body). Blocks [0,512): B-side x2 + bf16 pack.
// Blocks [512,1024): A-side 2 classes/block: member lists, gathered center,
// c2, counts, bf16 pack. Also: block 0 zeroes the done-counter; A-side
// initializes the per-class atomic min/max keys (workspace is poisoned
// between iterations, so every launch must rewrite these).
__global__ __launch_bounds__(256) void pack_kernel(
    const float* __restrict__ inputs, const int* __restrict__ targets,
    float* __restrict__ x2, float* __restrict__ c2, int* __restrict__ counts,
    short8* __restrict__ Apk, short8* __restrict__ Bpk,
    unsigned* __restrict__ dpk, unsigned* __restrict__ dnk,
    int* __restrict__ ctr) {
  int b = blockIdx.x;
  int tid = threadIdx.x;
  if (b == 0 && tid == 0) ctr[0] = 0;
  if (b < N_SAMPLES / 16) {
    int row = b * 16 + (tid >> 4);
    int oct = tid & 15;
    const float4* p = (const float4*)(inputs + (size_t)row * DIM + oct * 8);
    float4 v0 = p[0], v1 = p[1];
    float v[8] = {v0.x, v0.y, v0.z, v0.w, v1.x, v1.y, v1.z, v1.w};
    float s = 0.f;
    #pragma unroll
    for (int i = 0; i < 8; i++) s += v[i] * v[i];
    #pragma unroll
    for (int m = 1; m < 16; m <<= 1) s += __shfl_xor(s, m);
    if (oct == 0) x2[row] = s;
    short8 hi;
    #pragma unroll
    for (int i = 0; i < 8; i++) hi[i] = bf16_rne(v[i]);
    Bpk[frag_idx(row, oct)] = hi;
  } else {
    __shared__ int mem[2][MAXMEM];
    __shared__ int mcnt[2];
    __shared__ float sctr[2][128];
    __shared__ float wsum[4];
    int c0 = (b - N_SAMPLES / 16) * 2;
    if (tid < 2) { mcnt[tid] = 0; mem[tid][0] = 0; }  // mem[.][0] valid even if cnt==0
    __syncthreads();
    // batch-load all targets first (independent loads, no atomic interleave)
    int tg[N_SAMPLES / 256];
    #pragma unroll
    for (int i = 0; i < N_SAMPLES / 256; i++) tg[i] = targets[tid + 256 * i];
    #pragma unroll
    for (int i = 0; i < N_SAMPLES / 256; i++) {
      if (tg[i] == c0) {
        int p = atomicAdd(&mcnt[0], 1);
        if (p < MAXMEM) mem[0][p] = tid + 256 * i;
      } else if (tg[i] == c0 + 1) {
        int p = atomicAdd(&mcnt[1], 1);
        if (p < MAXMEM) mem[1][p] = tid + 256 * i;
      }
    }
    __syncthreads();
    int half = tid >> 7;
    int c = c0 + half;
    int d = tid & 127;
    int cnt = mcnt[half];
    int cl = (cnt < MAXMEM) ? cnt : MAXMEM;
    int n1 = (cl < PIPE) ? cl : PIPE;
    int idxs[PIPE];
    #pragma unroll
    for (int i = 0; i < PIPE; i++) idxs[i] = mem[half][(i < n1) ? i : 0];
    float vbuf[PIPE];
    #pragma unroll
    for (int i = 0; i < PIPE; i++) vbuf[i] = inputs[(size_t)idxs[i] * DIM + d];
    float acc = 0.f;
    #pragma unroll
    for (int i = 0; i < PIPE; i++) if (i < n1) acc += vbuf[i];
    for (int m = PIPE; m < cl; m++) acc += inputs[(size_t)mem[half][m] * DIM + d];
    float ctrv = (cnt > 0) ? acc / (float)cnt : 0.f;
    sctr[half][d] = ctrv;
    float vv = ctrv * ctrv;
    #pragma unroll
    for (int sh = 32; sh > 0; sh >>= 1) vv += __shfl_down(vv, sh);
    if ((tid & 63) == 0) wsum[tid >> 6] = vv;
    __syncthreads();
    if (d == 0) {
      c2[c] = wsum[half * 2] + wsum[half * 2 + 1];
      counts[c] = cnt;
      dpk[c] = 0u;           // identity for ordered-key max (= -NaN)
      dnk[c] = 0xFFFFFFFFu;  // identity for ordered-key min
    }
    if (d < 16) {
      int oct = d;
      short8 hi;
      #pragma unroll
      for (int i = 0; i < 8; i++) hi[i] = bf16_rne(sctr[half][oct * 8 + i]);
      Apk[frag_idx(c, oct)] = hi;
    }
  }
}

// K2: MFMA dist (verified body) + per-class device atomicMax/Min on ordered
// keys instead of the 512 KB partials round-trip + NON-BLOCKING last-block
// finalize: the block whose done-counter add returns NBLK-1 proceeds into
// the 12 KB final reduce and writes out[] directly. No thread ever spins on
// another block -> hang-impossible (lesson of rounds 1-2: grid-wide sync,
// spinning or cooperative, is not reliably available in this harness).
__global__ __launch_bounds__(256, 4) void dist_kernel(
    const short8* __restrict__ Apk, const short8* __restrict__ Bpk,
    const float* __restrict__ x2, const float* __restrict__ c2,
    const int* __restrict__ targets, const int* __restrict__ counts,
    unsigned* __restrict__ dpk, unsigned* __restrict__ dnk,
    int* __restrict__ ctr, float* __restrict__ out) {
  __shared__ float sc2[64];
  __shared__ float sx2[128];
  __shared__ int stgt[128];
  __shared__ float redp[2][2][32];  // [wn][wm][class-in-tile]
  __shared__ float redn[2][2][32];
  __shared__ int s_last;
  __shared__ float fred[8];

  int tid = threadIdx.x;
  int jbase = blockIdx.x * 128;
  int cbase = blockIdx.y * 64;
  int wave = tid >> 6, lane = tid & 63;
  int wm = wave >> 1, wn = wave & 1;

  if (tid < 128) {
    sx2[tid] = x2[jbase + tid];
    stgt[tid] = targets[jbase + tid];
  }
  if (tid < 64) sc2[tid] = c2[cbase + tid];

  int mtg = (cbase >> 5) + wm;       // this wave's m-tile in Apk
  int ntg0 = (jbase >> 5) + wn * 2;  // first of 2 n-tiles in Bpk

  f32x16 acc[2];
  acc[0] = (f32x16)(0.f);
  acc[1] = (f32x16)(0.f);

  #pragma unroll
  for (int ks = 0; ks < 8; ks++) {
    bf16x8 av = Apk[(size_t)(mtg * 8 + ks) * 64 + lane];
    bf16x8 b0 = Bpk[(size_t)((ntg0 + 0) * 8 + ks) * 64 + lane];
    bf16x8 b1 = Bpk[(size_t)((ntg0 + 1) * 8 + ks) * 64 + lane];
    acc[0] = __builtin_amdgcn_mfma_f32_32x32x16_bf16(av, b0, acc[0], 0, 0, 0);
    acc[1] = __builtin_amdgcn_mfma_f32_32x32x16_bf16(av, b1, acc[1], 0, 0, 0);
  }

  __syncthreads();  // staging visible

  int hf = lane >> 5;
  int col = lane & 31;
  #pragma unroll
  for (int r = 0; r < 16; r++) {
    int rowl = (r & 3) + 8 * (r >> 2) + 4 * hf;   // (r,hf) covers 0..31 once
    int c_loc = wm * 32 + rowl;
    int cg = cbase + c_loc;
    float c2v = sc2[c_loc];
    float pmax = -INFINITY, nmin = INFINITY;
    #pragma unroll
    for (int nt = 0; nt < 2; nt++) {
      int j_loc = wn * 64 + nt * 32 + col;
      float d2 = c2v + sx2[j_loc] - 2.f * acc[nt][r];
      if (stgt[j_loc] == cg) pmax = fmaxf(pmax, d2);
      else                   nmin = fminf(nmin, d2);
    }
    #pragma unroll
    for (int m = 1; m < 32; m <<= 1) {
      pmax = fmaxf(pmax, __shfl_xor(pmax, m));
      nmin = fminf(nmin, __shfl_xor(nmin, m));
    }
    if (col == 0) {  // lanes 0 (hf=0) and 32 (hf=1): distinct rowl
      redp[wn][wm][rowl] = pmax;
      redn[wn][wm][rowl] = nmin;
    }
  }
  __syncthreads();
  if (tid < 64) {  // one thread per class in this block's 64-class tile
    int wmx = tid >> 5, idx = tid & 31;
    float dp = fmaxf(redp[0][wmx][idx], redp[1][wmx][idx]);
    float dn = fminf(redn[0][wmx][idx], redn[1][wmx][idx]);
    atomicMax(&dpk[cbase + tid], f2ord(dp));   // device-scope (guide G12/m20)
    atomicMin(&dnk[cbase + tid], f2ord(dn));
  }

  // ---- non-blocking done-counter; last-finishing block finalizes ----
  __syncthreads();  // barrier drains this block's atomics (vmcnt(0))
  if (tid == 0) {
    __threadfence();
    int prev = __hip_atomic_fetch_add(ctr, 1, __ATOMIC_ACQ_REL,
                                      __HIP_MEMORY_SCOPE_AGENT);
    s_last = (prev == NBLK - 1) ? 1 : 0;
  }
  __syncthreads();
  if (!s_last) return;
  __threadfence();  // acquire side: all blocks' atomics now visible

  // Final epilogue (one block, 12 KB of reads): 4 classes/thread.
  float ls = 0.f, ps = 0.f;
  #pragma unroll
  for (int k = 0; k < 4; k++) {
    int c = tid + 256 * k;
    unsigned pk = __hip_atomic_load(&dpk[c], __ATOMIC_RELAXED,
                                    __HIP_MEMORY_SCOPE_AGENT);
    unsigned nk = __hip_atomic_load(&dnk[c], __ATOMIC_RELAXED,
                                    __HIP_MEMORY_SCOPE_AGENT);
    int cnt = counts[c];
    float dp = ord2f(pk), dn = ord2f(nk);
    if (cnt > 0) {
      ls += (float)cnt * fmaxf(dp - dn + MARGIN_V, 0.f);
      ps += (float)cnt * ((dn > dp) ? 1.f : 0.f);
    }
  }
  #pragma unroll
  for (int sh = 32; sh > 0; sh >>= 1) {
    ls += __shfl_down(ls, sh);
    ps += __shfl_down(ps, sh);
  }
  if (lane == 0) { fred[wave] = ls; fred[4 + wave] = ps; }
  __syncthreads();
  if (tid == 0) {
    out[0] = (fred[0] + fred[1] + fred[2] + fred[3]) / (float)N_SAMPLES;
    out[1] = (fred[4] + fred[5] + fred[6] + fred[7]) / (float)N_SAMPLES;
  }
}

extern "C" void kernel_launch(void* const* d_in, const int* in_sizes, int n_in,
                              void* d_out, int out_size, void* d_ws, size_t ws_size,
                              hipStream_t stream) {
  const float* inputs = (const float*)d_in[0];
  const int* targets = (const int*)d_in[1];
  float* out = (float*)d_out;

  char* w = (char*)d_ws;
  int* ctr = (int*)w;               w += 16;                          // done counter
  float* x2 = (float*)w;            w += (size_t)N_SAMPLES * 4;
  float* c2 = (float*)w;            w += (size_t)NCLS * 4;
  int* counts = (int*)w;            w += (size_t)NCLS * 4;
  unsigned* dpk = (unsigned*)w;     w += (size_t)NCLS * 4;            // ordered-key max
  unsigned* dnk = (unsigned*)w;     w += (size_t)NCLS * 4;            // ordered-key min
  short8* Apk = (short8*)w;         w += (size_t)NCLS * DIM * 2;      // 256 KB
  short8* Bpk = (short8*)w;         w += (size_t)N_SAMPLES * DIM * 2; // 2 MB

  pack_kernel<<<N_SAMPLES / 16 + NCLS / 2, 256, 0, stream>>>(
      inputs, targets, x2, c2, counts, Apk, Bpk, dpk, dnk, ctr);
  dist_kernel<<<dim3(DIST_GX, DIST_GY), 256, 0, stream>>>(
      Apk, Bpk, x2, c2, targets, counts, dpk, dnk, ctr, out);
}

// Round 4
// 69.882 us; speedup vs baseline: 1.4753x; 1.4753x over previous
//
#include <hip/hip_runtime.h>
#include <math.h>

#define N_SAMPLES 8192
#define DIM 128
#define NCLS 1024
#define MARGIN_V 0.3f
#define DIST_GX (N_SAMPLES / 128)   // 64 j-tiles of 128
#define DIST_GY (NCLS / 64)         // 16 class-tiles of 64
#define NPART DIST_GX               // 64 partials per class
#define MAXMEM 64                   // LDS member-list capacity per class
#define PIPE 16                     // pipelined gather depth (covers P(cnt<=16)~0.997)

using bf16x8 = __attribute__((ext_vector_type(8))) short;
using f32x16 = __attribute__((ext_vector_type(16))) float;
using short8 = __attribute__((ext_vector_type(8))) short;

__device__ __forceinline__ short bf16_rne(float x) {
  unsigned u = __float_as_uint(x);
  unsigned r = u + 0x7FFFu + ((u >> 16) & 1u);
  return (short)(r >> 16);
}

// Packed fragment layout, single bf16 plane (row-major source [row][k]):
//   tile = row>>5, kstep = oct>>1 (oct = k/8), lane = ((oct&1)<<5)|(row&31)
//   short8 index = (tile*8 + kstep)*64 + lane
// Matches mfma_32x32x16 A/B operand layout operand[row=lane&31][k=(lane>>5)*8+j]
// (harness-verified; bf16-only passes with absmax ~0).
__device__ __forceinline__ size_t frag_idx(int row, int oct) {
  int tile = row >> 5, ks = oct >> 1, lane = ((oct & 1) << 5) | (row & 31);
  return (size_t)(tile * 8 + ks) * 64 + lane;
}

// K1: fused pack — EXACT round-0 verified body (76.8 us session).
// Blocks [0,512): B-side — x2 + bf16 pack of 16 input rows.
// Blocks [512,1024): A-side — 2 classes/block. Block 0 zeroes out.
__global__ __launch_bounds__(256) void pack_kernel(
    const float* __restrict__ inputs, const int* __restrict__ targets,
    float* __restrict__ x2, float* __restrict__ c2, int* __restrict__ counts,
    short8* __restrict__ Apk, short8* __restrict__ Bpk, float* __restrict__ out) {
  int b = blockIdx.x;
  int tid = threadIdx.x;
  if (b == 0 && tid < 2) out[tid] = 0.f;
  if (b < N_SAMPLES / 16) {
    int row = b * 16 + (tid >> 4);
    int oct = tid & 15;
    const float4* p = (const float4*)(inputs + (size_t)row * DIM + oct * 8);
    float4 v0 = p[0], v1 = p[1];
    float v[8] = {v0.x, v0.y, v0.z, v0.w, v1.x, v1.y, v1.z, v1.w};
    float s = 0.f;
    #pragma unroll
    for (int i = 0; i < 8; i++) s += v[i] * v[i];
    #pragma unroll
    for (int m = 1; m < 16; m <<= 1) s += __shfl_xor(s, m);
    if (oct == 0) x2[row] = s;
    short8 hi;
    #pragma unroll
    for (int i = 0; i < 8; i++) hi[i] = bf16_rne(v[i]);
    Bpk[frag_idx(row, oct)] = hi;
  } else {
    __shared__ int mem[2][MAXMEM];
    __shared__ int mcnt[2];
    __shared__ float sctr[2][128];
    __shared__ float wsum[4];
    int c0 = (b - N_SAMPLES / 16) * 2;
    if (tid < 2) { mcnt[tid] = 0; mem[tid][0] = 0; }  // mem[.][0] valid even if cnt==0
    __syncthreads();
    // batch-load all targets first (independent loads, no atomic interleave)
    int tg[N_SAMPLES / 256];
    #pragma unroll
    for (int i = 0; i < N_SAMPLES / 256; i++) tg[i] = targets[tid + 256 * i];
    #pragma unroll
    for (int i = 0; i < N_SAMPLES / 256; i++) {
      if (tg[i] == c0) {
        int p = atomicAdd(&mcnt[0], 1);
        if (p < MAXMEM) mem[0][p] = tid + 256 * i;
      } else if (tg[i] == c0 + 1) {
        int p = atomicAdd(&mcnt[1], 1);
        if (p < MAXMEM) mem[1][p] = tid + 256 * i;
      }
    }
    __syncthreads();
    int half = tid >> 7;
    int c = c0 + half;
    int d = tid & 127;
    int cnt = mcnt[half];
    int cl = (cnt < MAXMEM) ? cnt : MAXMEM;
    int n1 = (cl < PIPE) ? cl : PIPE;
    int idxs[PIPE];
    #pragma unroll
    for (int i = 0; i < PIPE; i++) idxs[i] = mem[half][(i < n1) ? i : 0];
    float vbuf[PIPE];
    #pragma unroll
    for (int i = 0; i < PIPE; i++) vbuf[i] = inputs[(size_t)idxs[i] * DIM + d];
    float acc = 0.f;
    #pragma unroll
    for (int i = 0; i < PIPE; i++) if (i < n1) acc += vbuf[i];
    for (int m = PIPE; m < cl; m++) acc += inputs[(size_t)mem[half][m] * DIM + d];
    float ctrv = (cnt > 0) ? acc / (float)cnt : 0.f;
    sctr[half][d] = ctrv;
    float vv = ctrv * ctrv;
    #pragma unroll
    for (int sh = 32; sh > 0; sh >>= 1) vv += __shfl_down(vv, sh);
    if ((tid & 63) == 0) wsum[tid >> 6] = vv;
    __syncthreads();
    if (d == 0) {
      c2[c] = wsum[half * 2] + wsum[half * 2 + 1];
      counts[c] = cnt;
    }
    if (d < 16) {
      int oct = d;
      short8 hi;
      #pragma unroll
      for (int i = 0; i < 8; i++) hi[i] = bf16_rne(sctr[half][oct * 8 + i]);
      Apk[frag_idx(c, oct)] = hi;
    }
  }
}

// K2: MFMA dist, LATENCY-FIXED version.
// R3 post-mortem: VGPR_Count=36 proved the compiler serialized all 24 fragment
// loads through ~4 registers (acc[2] ate 32 of 36) -> 24 dependent L2-latency
// hops per wave; plus a 160-op dependent ds_swizzle epilogue chain. Fixes:
// (a) prefetch-all: av[8]/b0[8]/b1[8] register arrays (96 VGPR dests), loads
//     issued back-to-back from 3 base pointers with immediate offsets, ONE
//     latency exposure; __launch_bounds__(256,3) raises VGPR cap to ~170.
// (b) operand-swapped MFMA: mfma(b, a) -> D[j][class]: col=lane&31 is the
//     CLASS, rows/regs are j -> per-class max/min over j is lane-local VALU
//     (32 ops) + one shfl_xor(32) fold. Entire shuffle-chain epilogue gone.
// Partials: plain coalesced stores (R3's device-scope atomicMax went to
// memory-side - 608KB WRITE_SIZE - and regressed; reverted).
__global__ __launch_bounds__(256, 3) void dist_kernel(
    const short8* __restrict__ Apk, const short8* __restrict__ Bpk,
    const float* __restrict__ x2, const float* __restrict__ c2,
    const int* __restrict__ targets,
    float* __restrict__ dp_part, float* __restrict__ dn_part) {
  __shared__ float sc2[64];
  __shared__ float sx2[128];
  __shared__ int stgt[128];
  __shared__ float redp[2][2][32];  // [wn][wm][class-in-tile]
  __shared__ float redn[2][2][32];

  int tid = threadIdx.x;
  int jbase = blockIdx.x * 128;
  int cbase = blockIdx.y * 64;
  int wave = tid >> 6, lane = tid & 63;
  int wm = wave >> 1, wn = wave & 1;

  if (tid < 128) {
    sx2[tid] = x2[jbase + tid];
    stgt[tid] = targets[jbase + tid];
  }
  if (tid < 64) sc2[tid] = c2[cbase + tid];

  int mtg = (cbase >> 5) + wm;       // this wave's m-tile in Apk
  int ntg0 = (jbase >> 5) + wn * 2;  // first of 2 n-tiles in Bpk

  // ---- prefetch-all: 24 loads in flight (3 bases + immediate offsets) ----
  const short8* abase  = &Apk[(size_t)(mtg * 8) * 64 + lane];
  const short8* b0base = &Bpk[(size_t)((ntg0 + 0) * 8) * 64 + lane];
  const short8* b1base = &Bpk[(size_t)((ntg0 + 1) * 8) * 64 + lane];
  bf16x8 av[8], b0[8], b1[8];
  #pragma unroll
  for (int ks = 0; ks < 8; ks++) {
    av[ks] = abase[(size_t)ks * 64];    // offset ks*1024 B (13-bit imm fits)
    b0[ks] = b0base[(size_t)ks * 64];
    b1[ks] = b1base[(size_t)ks * 64];
  }

  f32x16 acc[2];
  acc[0] = (f32x16)(0.f);
  acc[1] = (f32x16)(0.f);

  // Swapped operands: D[row=j][col=class].
  #pragma unroll
  for (int ks = 0; ks < 8; ks++) {
    acc[0] = __builtin_amdgcn_mfma_f32_32x32x16_bf16(b0[ks], av[ks], acc[0], 0, 0, 0);
    acc[1] = __builtin_amdgcn_mfma_f32_32x32x16_bf16(b1[ks], av[ks], acc[1], 0, 0, 0);
  }

  __syncthreads();  // staging visible

  // ---- lane-local epilogue: lane owns class col=lane&31; regs span j ----
  int col = lane & 31;
  int hf = lane >> 5;
  int c_loc = wm * 32 + col;
  int cg = cbase + c_loc;
  float c2v = sc2[c_loc];
  float pmax = -INFINITY, nmin = INFINITY;
  #pragma unroll
  for (int nt = 0; nt < 2; nt++) {
    #pragma unroll
    for (int r = 0; r < 16; r++) {
      int j_loc = wn * 64 + nt * 32 + (r & 3) + 8 * (r >> 2) + 4 * hf;
      float d2 = c2v + sx2[j_loc] - 2.f * acc[nt][r];
      if (stgt[j_loc] == cg) pmax = fmaxf(pmax, d2);
      else                   nmin = fminf(nmin, d2);
    }
  }
  // fold the two hf halves (same class, disjoint j sets)
  pmax = fmaxf(pmax, __shfl_xor(pmax, 32));
  nmin = fminf(nmin, __shfl_xor(nmin, 32));
  if (lane < 32) {
    redp[wn][wm][col] = pmax;
    redn[wn][wm][col] = nmin;
  }
  __syncthreads();
  if (tid < 64) {  // one thread per class in this block's 64-class tile
    int wmx = tid >> 5, idx = tid & 31;
    float dp = fmaxf(redp[0][wmx][idx], redp[1][wmx][idx]);
    float dn = fminf(redn[0][wmx][idx], redn[1][wmx][idx]);
    size_t slot = (size_t)blockIdx.x * NCLS + cbase + tid;
    dp_part[slot] = dp;
    dn_part[slot] = dn;
  }
}

// K3: EXACT round-0 verified body. 16 blocks x 256 threads; one atomicAdd
// pair per block into out (zeroed by K1).
__global__ __launch_bounds__(256) void finalize_kernel(
    const float* __restrict__ dp_part, const float* __restrict__ dn_part,
    const int* __restrict__ counts, float* __restrict__ out) {
  __shared__ float sdp[4][64];
  __shared__ float sdn[4][64];
  int g = blockIdx.x;
  int t = threadIdx.x;
  int cl = t & 63;
  int pg = t >> 6;
  int c = g * 64 + cl;
  float dp = -INFINITY, dn = INFINITY;
  #pragma unroll
  for (int p = pg * 16; p < pg * 16 + 16; p++) {
    dp = fmaxf(dp, dp_part[(size_t)p * NCLS + c]);
    dn = fminf(dn, dn_part[(size_t)p * NCLS + c]);
  }
  sdp[pg][cl] = dp;
  sdn[pg][cl] = dn;
  __syncthreads();
  if (t < 64) {  // wave 0
    dp = fmaxf(fmaxf(sdp[0][cl], sdp[1][cl]), fmaxf(sdp[2][cl], sdp[3][cl]));
    dn = fminf(fminf(sdn[0][cl], sdn[1][cl]), fminf(sdn[2][cl], sdn[3][cl]));
    int cnt = counts[c];
    float ls = 0.f, ps = 0.f;
    if (cnt > 0) {
      ls = (float)cnt * fmaxf(dp - dn + MARGIN_V, 0.f);
      ps = (float)cnt * ((dn > dp) ? 1.f : 0.f);
    }
    #pragma unroll
    for (int sh = 32; sh > 0; sh >>= 1) {
      ls += __shfl_down(ls, sh);
      ps += __shfl_down(ps, sh);
    }
    if (t == 0) {
      atomicAdd(&out[0], ls / (float)N_SAMPLES);
      atomicAdd(&out[1], ps / (float)N_SAMPLES);
    }
  }
}

extern "C" void kernel_launch(void* const* d_in, const int* in_sizes, int n_in,
                              void* d_out, int out_size, void* d_ws, size_t ws_size,
                              hipStream_t stream) {
  const float* inputs = (const float*)d_in[0];
  const int* targets = (const int*)d_in[1];
  float* out = (float*)d_out;

  char* w = (char*)d_ws;
  float* x2 = (float*)w;            w += (size_t)N_SAMPLES * 4;
  float* c2 = (float*)w;            w += (size_t)NCLS * 4;
  int* counts = (int*)w;            w += (size_t)NCLS * 4;
  float* dp_part = (float*)w;       w += (size_t)NPART * NCLS * 4;    // 256 KB
  float* dn_part = (float*)w;       w += (size_t)NPART * NCLS * 4;    // 256 KB
  short8* Apk = (short8*)w;         w += (size_t)NCLS * DIM * 2;      // 256 KB
  short8* Bpk = (short8*)w;         w += (size_t)N_SAMPLES * DIM * 2; // 2 MB

  pack_kernel<<<N_SAMPLES / 16 + NCLS / 2, 256, 0, stream>>>(
      inputs, targets, x2, c2, counts, Apk, Bpk, out);
  dist_kernel<<<dim3(DIST_GX, DIST_GY), 256, 0, stream>>>(
      Apk, Bpk, x2, c2, targets, dp_part, dn_part);
  finalize_kernel<<<16, 256, 0, stream>>>(dp_part, dn_part, counts, out);
}